// Round 1
// 203.357 us; speedup vs baseline: 1.0372x; 1.0372x over previous
//
#include <hip/hip_runtime.h>
#include <stdint.h>

#define NN 50000
#define NE 800000
#define D  128
#define NEG_INIT -1e9f
#define CAP 64                            // bucket capacity per node (Poisson(16); P(deg>64)~1e-19)
#define OVF_CAP 131072

// ---------------- ws layout (int offsets) ----------------
#define CNT_OFF     64                    // NN counters, padded: 1 per 64B line (atomic spread)
#define CNT_STRIDE  16
#define OVF_CNT_OFF (CNT_OFF + NN * CNT_STRIDE)     // 800064 (zeroed by same memset)
#define OVF_OFF     (OVF_CNT_OFF + 4)               // 800068: OVF_CAP pairs (dst, entry)
#define BKT_OFF     1062400               // NN*CAP packed entries: (w_bf16<<16)|src ; 0xFF-memset = NaN pad
#define XBF_OFF     (BKT_OFF + NN * CAP)            // 4262400: NN*D bf16 x
#define WBF_OFF     (XBF_OFF + NN * (D / 2))        // 7462400: w1+w2 bf16
// total: 7,478,784 ints = 29.9 MB (< 32.4 MB proven available)

#define HSTRIDE 136                       // LDS row stride in ushorts (272 B, 2-way banks = free)

// fused prep+fill block ranges
#define FILL_BLKS 3125                    // NE/256
#define PX_BLKS   6250                    // NN*D/1024
#define PW_BLKS   32

typedef __attribute__((ext_vector_type(8))) short short8;
typedef __attribute__((ext_vector_type(4))) float float4v;

// ---------------- bf16 helpers ----------------
__device__ __forceinline__ float b2f(uint16_t u) {
    union { uint32_t u; float f; } v; v.u = ((uint32_t)u) << 16; return v.f;
}
__device__ __forceinline__ float ubits(uint32_t u) {
    union { uint32_t u; float f; } v; v.u = u; return v.f;
}
__device__ __forceinline__ uint16_t f2b(float f) {
    union { float f; uint32_t u; } v; v.f = f;
    uint32_t r = v.u + 0x7fffu + ((v.u >> 16) & 1u);   // RNE
    return (uint16_t)(r >> 16);
}

// ---------------- per-block inline dtype probe (load-bearing; rounds 2-9) ----------------
__device__ __forceinline__ void block_probe(const uint16_t* __restrict__ xraw,
                                            const int* __restrict__ eraw,
                                            int* sflags) {
    int t = threadIdx.x;
    if (t < 64) {                                   // wave 0 only
        float v0 = b2f(xraw[2 * t]);
        float v1 = b2f(xraw[2 * t + 1]);
        int bad = (!(v0 > -1e4f && v0 < 1e4f)) || (!(v1 > -1e4f && v1 < 1e4f));
        unsigned long long bm = __ballot(bad);
        int nz = (t < 32) ? (eraw[2 * t + 1] != 0) : 0;
        unsigned long long im = __ballot(nz);
        if (t == 0) { sflags[0] = bm ? 1 : 0; sflags[1] = im ? 0 : 1; }
    }
    __syncthreads();
}

// ---------------- fused fill + prep_x + prep_w ----------------
// fill blocks FIRST (latency-bound atomics start early; prep_x streaming
// overlaps on the same CUs). Counters pre-zeroed; buckets pre-0xFF'd (NaN pad).
__global__ __launch_bounds__(256) void prep_fill_kernel(
    const uint16_t* __restrict__ xraw,
    const int*      __restrict__ eraw,
    const uint16_t* __restrict__ ewraw,
    const uint16_t* __restrict__ w1raw,
    const uint16_t* __restrict__ w2raw,
    int* __restrict__ ws)
{
    __shared__ int sflags[2];
    block_probe(xraw, eraw, sflags);
    const int f32 = sflags[0], i64 = sflags[1];

    int bid = blockIdx.x;
    if (bid < FILL_BLKS) {
        // ---- edge fill: one packed 4 B entry per edge ----
        int e = bid * 256 + threadIdx.x;
        int src, dst;
        if (i64) {
            const long long* e64 = (const long long*)eraw;
            src = (int)e64[e];
            dst = (int)e64[NE + e];
        } else {
            src = eraw[e];
            dst = eraw[NE + e];
        }
        if ((unsigned)src >= NN || (unsigned)dst >= NN) return;
        uint w = f32 ? (uint)f2b(((const float*)ewraw)[e]) : (uint)ewraw[e];
        uint entry = (w << 16) | (uint)src;
        int slot = atomicAdd(ws + CNT_OFF + dst * CNT_STRIDE, 1);
        if (slot < CAP) {
            ((uint*)(ws + BKT_OFF))[(size_t)dst * CAP + slot] = entry;
        } else {
            int o = atomicAdd(ws + OVF_CNT_OFF, 1);
            if (o < OVF_CAP) {
                ws[OVF_OFF + 2 * o]     = dst;
                ws[OVF_OFF + 2 * o + 1] = (int)entry;
            }
        }
    } else if (bid < FILL_BLKS + PX_BLKS) {
        // ---- x -> bf16 table ----
        int i4 = ((bid - FILL_BLKS) * 256 + threadIdx.x) * 4;   // covers NN*D exactly
        ushort* dst = (ushort*)(ws + XBF_OFF);
        if (f32) {
            float4 v = *(const float4*)((const float*)xraw + i4);
            ushort4 o; o.x = f2b(v.x); o.y = f2b(v.y); o.z = f2b(v.z); o.w = f2b(v.w);
            *(ushort4*)(dst + i4) = o;
        } else {
            *(ushort4*)(dst + i4) = *(const ushort4*)(xraw + i4);
        }
    } else {
        // ---- w1,w2 -> bf16 table ----
        int i4 = ((bid - FILL_BLKS - PX_BLKS) * 256 + threadIdx.x) * 4; // 0..32764
        const uint16_t* src = (i4 < 16384) ? w1raw : w2raw;
        int off = i4 & 16383;
        ushort* dst = (ushort*)(ws + WBF_OFF);
        if (f32) {
            float4 v = *(const float4*)((const float*)src + off);
            ushort4 o; o.x = f2b(v.x); o.y = f2b(v.y); o.z = f2b(v.z); o.w = f2b(v.w);
            *(ushort4*)(dst + i4) = o;
        } else {
            *(ushort4*)(dst + i4) = *(const ushort4*)(src + off);
        }
    }
}

// ---------------- fused gather-max + MFMA MLP ----------------
// 16 nodes/block, 4 waves; wave gathers 4 nodes (lane = dim pair), unroll-16
// with uint4 bucket-entry loads (16 outstanding row-gathers). Then MFMA.
// NaN-pad trick: unfilled bucket slots are 0xFFFFFFFF -> w = bf16 NaN ->
// product NaN -> IEEE v_max drops it. No per-edge validity mask needed.
// A[m=lane&15][k=quad*8+j]; C/D: col=lane&15, row=quad*4+reg.
__global__ __launch_bounds__(256) void gmlp_kernel(
    const uint16_t* __restrict__ xraw,
    const int*      __restrict__ eraw,
    const uint16_t* __restrict__ b1raw,
    const uint16_t* __restrict__ b2raw,
    const uint16_t* __restrict__ epsraw,
    const int* __restrict__ ws,
    uint16_t* __restrict__ outraw)
{
    __shared__ int    sflags[2];
    __shared__ uint   tl[16 * (HSTRIDE / 2)];   // t tile, 68 uints/row
    __shared__ ushort hl[16 * HSTRIDE];         // hidden tile

    block_probe(xraw, eraw, sflags);
    const int f32 = sflags[0];

    const int tid  = threadIdx.x;
    const int wave = tid >> 6;
    const int lane = tid & 63;
    const int m    = lane & 15;
    const int quad = lane >> 4;
    const int node0 = blockIdx.x * 16;

    const ushort* w1b = (const ushort*)(ws + WBF_OFF);
    const ushort* w2b = w1b + 16384;
    const uint*   xbf = (const uint*)(ws + XBF_OFF);
    const uint*   bkt = (const uint*)(ws + BKT_OFF);

    const float eps1 = 1.0f + (f32 ? ((const float*)epsraw)[0] : b2f(epsraw[0]));

    // hoist the 4 per-node degree loads (breaks the dependent-load stall per node)
    int cr[4];
    #pragma unroll
    for (int j = 0; j < 4; ++j)
        cr[j] = ws[CNT_OFF + (wave * 4 + j + node0) * CNT_STRIDE];

    // gather phase: 4 nodes per wave, lane covers dims (2*lane, 2*lane+1)
    for (int j = 0; j < 4; ++j) {
        int nl = wave * 4 + j;
        int n  = node0 + nl;
        int cnt_raw = cr[j];
        int cnt = (cnt_raw < CAP) ? cnt_raw : CAP;

        float m0[16], m1[16];
        #pragma unroll
        for (int u = 0; u < 16; ++u) { m0[u] = NEG_INIT; m1[u] = NEG_INIT; }

        const uint* brow = bkt + (size_t)n * CAP;
        for (int i = 0; i < cnt; i += 16) {
            uint4 q[4];
            #pragma unroll
            for (int qq = 0; qq < 4; ++qq) q[qq] = *(const uint4*)(brow + i + qq * 4);
            #pragma unroll
            for (int u = 0; u < 16; ++u) {
                uint e0  = ((const uint*)q)[u];
                uint idx = e0 & 0xffffu;
                idx = min(idx, (uint)(NN - 1));        // pad src 0xFFFF -> in-bounds hot row
                uint v = xbf[idx * 64 + lane];
                float w  = ubits(e0 & 0xffff0000u);    // pad -> NaN, drops out of max
                float p0 = ubits(v << 16) * w;
                float p1 = ubits(v & 0xffff0000u) * w;
                m0[u] = fmaxf(m0[u], p0);
                m1[u] = fmaxf(m1[u], p1);
            }
        }
        // overflow edges (exactness insurance; statistically never taken)
        if (cnt_raw > CAP) {
            int novf = ws[OVF_CNT_OFF];
            if (novf > OVF_CAP) novf = OVF_CAP;
            for (int o = 0; o < novf; ++o) {
                if (ws[OVF_OFF + 2 * o] == n) {
                    uint e0 = (uint)ws[OVF_OFF + 2 * o + 1];
                    uint v  = xbf[(e0 & 0xffff) * 64 + lane];
                    float w = b2f((uint16_t)(e0 >> 16));
                    m0[0] = fmaxf(m0[0], b2f((uint16_t)v) * w);
                    m1[0] = fmaxf(m1[0], b2f((uint16_t)(v >> 16)) * w);
                }
            }
        }
        #pragma unroll
        for (int u = 8; u > 0; u >>= 1)
            #pragma unroll
            for (int v2 = 0; v2 < u; ++v2) {
                m0[v2] = fmaxf(m0[v2], m0[v2 + u]);
                m1[v2] = fmaxf(m1[v2], m1[v2 + u]);
            }
        float mx = m0[0], my = m1[0];
        if (cnt_raw == 0) { mx = 0.f; my = 0.f; }        // isolated node -> 0

        // self term from bf16 table (cache-hot)
        uint xv = xbf[(size_t)n * 64 + lane];
        float t0 = eps1 * b2f((uint16_t)xv) + mx;
        float t1 = eps1 * b2f((uint16_t)(xv >> 16)) + my;
        tl[nl * (HSTRIDE / 2) + lane] = (uint)f2b(t0) | ((uint)f2b(t1) << 16);
    }
    __syncthreads();

    // A frags from LDS t tile
    short8 a[4];
    {
        const ushort* arow = (const ushort*)tl + m * HSTRIDE + quad * 8;
        #pragma unroll
        for (int kb = 0; kb < 4; ++kb) a[kb] = *(const short8*)(arow + kb * 32);
    }

    // GEMM1 + bias + LeakyReLU -> hl
    #pragma unroll
    for (int t = 0; t < 2; ++t) {
        int ct = wave * 2 + t;
        float4v c = {0.f, 0.f, 0.f, 0.f};
        const ushort* brow = w1b + (size_t)(ct * 16 + m) * 128 + quad * 8;
        #pragma unroll
        for (int kb = 0; kb < 4; ++kb)
            c = __builtin_amdgcn_mfma_f32_16x16x32_bf16(a[kb], *(const short8*)(brow + kb * 32), c, 0, 0, 0);
        float bias = f32 ? ((const float*)b1raw)[ct * 16 + m] : b2f(b1raw[ct * 16 + m]);
        #pragma unroll
        for (int r = 0; r < 4; ++r) {
            float v = c[r] + bias;
            v = (v >= 0.f) ? v : 0.01f * v;
            hl[(quad * 4 + r) * HSTRIDE + ct * 16 + m] = f2b(v);
        }
    }
    __syncthreads();

    // A frags for GEMM2 from hl
    short8 ah[4];
    {
        const ushort* hrow = hl + m * HSTRIDE + quad * 8;
        #pragma unroll
        for (int kb = 0; kb < 4; ++kb) ah[kb] = *(const short8*)(hrow + kb * 32);
    }

    // GEMM2 + bias -> out
    #pragma unroll
    for (int t = 0; t < 2; ++t) {
        int ct = wave * 2 + t;
        float4v c = {0.f, 0.f, 0.f, 0.f};
        const ushort* brow = w2b + (size_t)(ct * 16 + m) * 128 + quad * 8;
        #pragma unroll
        for (int kb = 0; kb < 4; ++kb)
            c = __builtin_amdgcn_mfma_f32_16x16x32_bf16(ah[kb], *(const short8*)(brow + kb * 32), c, 0, 0, 0);
        float bias = f32 ? ((const float*)b2raw)[ct * 16 + m] : b2f(b2raw[ct * 16 + m]);
        #pragma unroll
        for (int r = 0; r < 4; ++r) {
            float v = c[r] + bias;
            size_t o = (size_t)(node0 + quad * 4 + r) * 128 + ct * 16 + m;
            if (f32) ((float*)outraw)[o] = v;
            else     outraw[o] = f2b(v);
        }
    }
}

// ================= host =================
extern "C" void kernel_launch(void* const* d_in, const int* in_sizes, int n_in,
                              void* d_out, int out_size, void* d_ws, size_t ws_size,
                              hipStream_t stream) {
    const uint16_t* x    = (const uint16_t*)d_in[0];
    const int*      eidx = (const int*)     d_in[1];
    const uint16_t* ew   = (const uint16_t*)d_in[2];
    const uint16_t* w1   = (const uint16_t*)d_in[3];
    const uint16_t* b1   = (const uint16_t*)d_in[4];
    const uint16_t* w2   = (const uint16_t*)d_in[5];
    const uint16_t* b2   = (const uint16_t*)d_in[6];
    const uint16_t* eps  = (const uint16_t*)d_in[7];
    uint16_t*       out  = (uint16_t*)d_out;
    int* ws = (int*)d_ws;

    // zero padded node counters + overflow counter (graph-capture-safe async memset)
    hipMemsetAsync((char*)d_ws + (size_t)CNT_OFF * 4, 0,
                   ((size_t)NN * CNT_STRIDE + 1) * 4, stream);
    // 0xFF-fill buckets: unfilled slot = (w=bf16 NaN | src=0xFFFF) -> NaN pad entry
    hipMemsetAsync((char*)d_ws + (size_t)BKT_OFF * 4, 0xFF,
                   (size_t)NN * CAP * 4, stream);
    prep_fill_kernel<<<FILL_BLKS + PX_BLKS + PW_BLKS, 256, 0, stream>>>(
        x, eidx, ew, w1, w2, ws);
    gmlp_kernel<<<NN / 16, 256, 0, stream>>>(x, eidx, b1, b2, eps, ws, out);
}

// Round 2
// 195.536 us; speedup vs baseline: 1.0787x; 1.0400x over previous
//
#include <hip/hip_runtime.h>
#include <stdint.h>

#define NN 50000
#define NE 800000
#define D  128
#define CAP 64                            // bucket capacity per node (Poisson(16); P(deg>64)~1e-19)
#define OVF_CAP 131072

// ---------------- ws layout (int offsets) ----------------
// Counters init to -1 via the single 0xFF memset (slot = atomicAdd()+1).
#define CNT_OFF     64                    // NN counters (stride 1; padding proven neutral in R1)
#define OVF_CNT_OFF (CNT_OFF + NN)        // 50064
#define OVF_OFF     (OVF_CNT_OFF + 4)     // 50068: OVF_CAP pairs (dst, entry)
#define BKT_OFF     312320                // NN*CAP packed entries: (w_fp16<<16)|src ; 0xFF = NaN pad
#define XH_OFF      (BKT_OFF + NN * CAP)  // 3512320: x as fp16 pairs; addressed as 65536 logical
                                          // rows so pad src 0xFFFF reads in-bounds garbage (NaN-dropped)
#define WH_OFF      (XH_OFF + 65536 * (D / 2))      // 7706624: w1+w2 fp16
// total high-water: 7,723,008 ints = 30.9 MB (< 32.4 MB proven available)

#define HSTRIDE 136                       // LDS row stride in ushorts (272 B, 2-way banks = free)

// fused prep+fill block ranges
#define FILL_BLKS 3125                    // NE/256
#define PX_BLKS   6250                    // NN*D/1024
#define PW_BLKS   32

typedef _Float16 half8 __attribute__((ext_vector_type(8)));
typedef __attribute__((ext_vector_type(4))) float float4v;

// ---------------- dtype helpers ----------------
__device__ __forceinline__ float b2f(uint16_t u) {
    union { uint32_t u; float f; } v; v.u = ((uint32_t)u) << 16; return v.f;
}
__device__ __forceinline__ uint16_t f2b(float f) {
    union { float f; uint32_t u; } v; v.f = f;
    uint32_t r = v.u + 0x7fffu + ((v.u >> 16) & 1u);   // RNE
    return (uint16_t)(r >> 16);
}
__device__ __forceinline__ ushort f2h(float f) {
    union { _Float16 h; ushort u; } v; v.h = (_Float16)f; return v.u;   // v_cvt_f16_f32 (RNE)
}
__device__ __forceinline__ float h2f(ushort u) {
    union { ushort u; _Float16 h; } v; v.u = u; return (float)v.h;
}

// ---------------- per-block inline dtype probe (load-bearing; rounds 2-9) ----------------
__device__ __forceinline__ void block_probe(const uint16_t* __restrict__ xraw,
                                            const int* __restrict__ eraw,
                                            int* sflags) {
    int t = threadIdx.x;
    if (t < 64) {                                   // wave 0 only
        float v0 = b2f(xraw[2 * t]);
        float v1 = b2f(xraw[2 * t + 1]);
        int bad = (!(v0 > -1e4f && v0 < 1e4f)) || (!(v1 > -1e4f && v1 < 1e4f));
        unsigned long long bm = __ballot(bad);
        int nz = (t < 32) ? (eraw[2 * t + 1] != 0) : 0;
        unsigned long long im = __ballot(nz);
        if (t == 0) { sflags[0] = bm ? 1 : 0; sflags[1] = im ? 0 : 1; }
    }
    __syncthreads();
}

// ---------------- fused fill + prep_x + prep_w ----------------
__global__ __launch_bounds__(256) void prep_fill_kernel(
    const uint16_t* __restrict__ xraw,
    const int*      __restrict__ eraw,
    const uint16_t* __restrict__ ewraw,
    const uint16_t* __restrict__ w1raw,
    const uint16_t* __restrict__ w2raw,
    int* __restrict__ ws)
{
    __shared__ int sflags[2];
    block_probe(xraw, eraw, sflags);
    const int f32 = sflags[0], i64 = sflags[1];

    int bid = blockIdx.x;
    if (bid < FILL_BLKS) {
        // ---- edge fill: one packed 4 B entry per edge ----
        int e = bid * 256 + threadIdx.x;
        int src, dst;
        if (i64) {
            const long long* e64 = (const long long*)eraw;
            src = (int)e64[e];
            dst = (int)e64[NE + e];
        } else {
            src = eraw[e];
            dst = eraw[NE + e];
        }
        if ((unsigned)src >= NN || (unsigned)dst >= NN) return;
        uint w = f32 ? (uint)f2h(((const float*)ewraw)[e]) : (uint)f2h(b2f(ewraw[e]));
        uint entry = (w << 16) | (uint)src;
        int slot = atomicAdd(ws + CNT_OFF + dst, 1) + 1;     // counter starts at -1
        if (slot < CAP) {
            ((uint*)(ws + BKT_OFF))[(size_t)dst * CAP + slot] = entry;
        } else {
            int o = atomicAdd(ws + OVF_CNT_OFF, 1) + 1;      // starts at -1
            if (o < OVF_CAP) {
                ws[OVF_OFF + 2 * o]     = dst;
                ws[OVF_OFF + 2 * o + 1] = (int)entry;
            }
        }
    } else if (bid < FILL_BLKS + PX_BLKS) {
        // ---- x -> fp16 table ----
        int i4 = ((bid - FILL_BLKS) * 256 + threadIdx.x) * 4;   // covers NN*D exactly
        ushort* dst = (ushort*)(ws + XH_OFF);
        if (f32) {
            float4 v = *(const float4*)((const float*)xraw + i4);
            ushort4 o; o.x = f2h(v.x); o.y = f2h(v.y); o.z = f2h(v.z); o.w = f2h(v.w);
            *(ushort4*)(dst + i4) = o;
        } else {
            ushort4 v = *(const ushort4*)(xraw + i4);
            ushort4 o; o.x = f2h(b2f(v.x)); o.y = f2h(b2f(v.y));
            o.z = f2h(b2f(v.z)); o.w = f2h(b2f(v.w));
            *(ushort4*)(dst + i4) = o;
        }
    } else {
        // ---- w1,w2 -> fp16 table ----
        int i4 = ((bid - FILL_BLKS - PX_BLKS) * 256 + threadIdx.x) * 4; // 0..32764
        const uint16_t* src = (i4 < 16384) ? w1raw : w2raw;
        int off = i4 & 16383;
        ushort* dst = (ushort*)(ws + WH_OFF);
        if (f32) {
            float4 v = *(const float4*)((const float*)src + off);
            ushort4 o; o.x = f2h(v.x); o.y = f2h(v.y); o.z = f2h(v.z); o.w = f2h(v.w);
            *(ushort4*)(dst + i4) = o;
        } else {
            ushort4 v = *(const ushort4*)(src + off);
            ushort4 o; o.x = f2h(b2f(v.x)); o.y = f2h(b2f(v.y));
            o.z = f2h(b2f(v.z)); o.w = f2h(b2f(v.w));
            *(ushort4*)(dst + i4) = o;
        }
    }
}

// ---------------- fused gather-max + MFMA MLP ----------------
// 16 nodes/block, 4 waves; wave gathers 4 nodes (lane = fp16 dim pair), unroll-16
// with uint4 bucket-entry loads (16 outstanding row-gathers). Then f16 MFMA.
// Packed-fp16 gather: per edge = {v_and, v_lshl_add, global_load,
// v_pk_mul_f16 (op_sel broadcasts the hi-16 weight), v_pk_max_f16}.
// NaN pad (0xFFFF = fp16 NaN) drops out of IEEE maxnum; pad src 0xFFFF reads
// in-bounds garbage from the 65536-row logical table (garbage * NaN = NaN).
__global__ __launch_bounds__(256) void gmlp_kernel(
    const uint16_t* __restrict__ xraw,
    const int*      __restrict__ eraw,
    const uint16_t* __restrict__ b1raw,
    const uint16_t* __restrict__ b2raw,
    const uint16_t* __restrict__ epsraw,
    const int* __restrict__ ws,
    uint16_t* __restrict__ outraw)
{
    __shared__ int    sflags[2];
    __shared__ uint   tl[16 * (HSTRIDE / 2)];   // t tile, 68 uints/row
    __shared__ ushort hl[16 * HSTRIDE];         // hidden tile

    block_probe(xraw, eraw, sflags);
    const int f32 = sflags[0];

    const int tid  = threadIdx.x;
    const int wave = tid >> 6;
    const int lane = tid & 63;
    const int m    = lane & 15;
    const int quad = lane >> 4;
    const int node0 = blockIdx.x * 16;

    const ushort* w1h = (const ushort*)(ws + WH_OFF);
    const ushort* w2h = w1h + 16384;
    const uint*   xh  = (const uint*)(ws + XH_OFF);
    const uint*   bkt = (const uint*)(ws + BKT_OFF);
    const uint    lane4 = (uint)lane * 4;

    const float eps1 = 1.0f + (f32 ? ((const float*)epsraw)[0] : b2f(epsraw[0]));

    // hoist the 4 per-node degree loads (breaks the dependent-load stall per node)
    int cr[4];
    #pragma unroll
    for (int j = 0; j < 4; ++j)
        cr[j] = ws[CNT_OFF + node0 + wave * 4 + j];          // = deg-1 (-1 if isolated)

    // gather phase: 4 nodes per wave, lane covers dims (2*lane, 2*lane+1)
    for (int j = 0; j < 4; ++j) {
        int nl = wave * 4 + j;
        int n  = node0 + nl;
        int deg = cr[j] + 1;
        int cnt = (deg < CAP) ? deg : CAP;

        uint mm[16];
        #pragma unroll
        for (int u = 0; u < 16; ++u) mm[u] = 0xFFFFFFFFu;    // packed fp16 NaN,NaN

        const uint* brow = bkt + (size_t)n * CAP;
        for (int i = 0; i < cnt; i += 16) {
            uint4 q[4];
            #pragma unroll
            for (int qq = 0; qq < 4; ++qq) q[qq] = *(const uint4*)(brow + i + qq * 4);
            #pragma unroll
            for (int u = 0; u < 16; ++u) {
                uint e0  = ((const uint*)q)[u];
                uint off = ((e0 & 0xffffu) << 8) + lane4;     // byte offset into fp16 table
                uint v   = *(const uint*)((const char*)xh + off);
                uint p;
                asm("v_pk_mul_f16 %0, %1, %2 op_sel:[0,1] op_sel_hi:[1,1]"
                    : "=v"(p) : "v"(v), "v"(e0));             // both halves * w (hi16 of e0)
                asm("v_pk_max_f16 %0, %0, %1" : "+v"(mm[u]) : "v"(p));
            }
        }
        #pragma unroll
        for (int u = 8; u > 0; u >>= 1)
            #pragma unroll
            for (int v2 = 0; v2 < u; ++v2)
                asm("v_pk_max_f16 %0, %0, %1" : "+v"(mm[v2]) : "v"(mm[v2 + u]));

        float mx = h2f((ushort)(mm[0] & 0xffffu));
        float my = h2f((ushort)(mm[0] >> 16));

        // overflow edges (exactness insurance; statistically never taken)
        if (deg > CAP) {
            int novf = ws[OVF_CNT_OFF] + 1;
            if (novf > OVF_CAP) novf = OVF_CAP;
            for (int o = 0; o < novf; ++o) {
                if (ws[OVF_OFF + 2 * o] == n) {
                    uint e0 = (uint)ws[OVF_OFF + 2 * o + 1];
                    uint v  = xh[(e0 & 0xffffu) * 64 + lane];
                    float w = h2f((ushort)(e0 >> 16));
                    mx = fmaxf(mx, h2f((ushort)(v & 0xffffu)) * w);
                    my = fmaxf(my, h2f((ushort)(v >> 16)) * w);
                }
            }
        }
        if (deg == 0) { mx = 0.f; my = 0.f; }                // isolated node -> 0

        // self term from fp16 table (cache-hot)
        uint xv = xh[(size_t)n * 64 + lane];
        float t0 = eps1 * h2f((ushort)(xv & 0xffffu)) + mx;
        float t1 = eps1 * h2f((ushort)(xv >> 16)) + my;
        tl[nl * (HSTRIDE / 2) + lane] = (uint)f2h(t0) | ((uint)f2h(t1) << 16);
    }
    __syncthreads();

    // A frags from LDS t tile
    half8 a[4];
    {
        const ushort* arow = (const ushort*)tl + m * HSTRIDE + quad * 8;
        #pragma unroll
        for (int kb = 0; kb < 4; ++kb) a[kb] = *(const half8*)(arow + kb * 32);
    }

    // GEMM1 + bias + LeakyReLU -> hl
    #pragma unroll
    for (int t = 0; t < 2; ++t) {
        int ct = wave * 2 + t;
        float4v c = {0.f, 0.f, 0.f, 0.f};
        const ushort* brow = w1h + (size_t)(ct * 16 + m) * 128 + quad * 8;
        #pragma unroll
        for (int kb = 0; kb < 4; ++kb)
            c = __builtin_amdgcn_mfma_f32_16x16x32_f16(a[kb], *(const half8*)(brow + kb * 32), c, 0, 0, 0);
        float bias = f32 ? ((const float*)b1raw)[ct * 16 + m] : b2f(b1raw[ct * 16 + m]);
        #pragma unroll
        for (int r = 0; r < 4; ++r) {
            float v = c[r] + bias;
            v = (v >= 0.f) ? v : 0.01f * v;
            hl[(quad * 4 + r) * HSTRIDE + ct * 16 + m] = f2h(v);
        }
    }
    __syncthreads();

    // A frags for GEMM2 from hl
    half8 ah[4];
    {
        const ushort* hrow = hl + m * HSTRIDE + quad * 8;
        #pragma unroll
        for (int kb = 0; kb < 4; ++kb) ah[kb] = *(const half8*)(hrow + kb * 32);
    }

    // GEMM2 + bias -> out
    #pragma unroll
    for (int t = 0; t < 2; ++t) {
        int ct = wave * 2 + t;
        float4v c = {0.f, 0.f, 0.f, 0.f};
        const ushort* brow = w2h + (size_t)(ct * 16 + m) * 128 + quad * 8;
        #pragma unroll
        for (int kb = 0; kb < 4; ++kb)
            c = __builtin_amdgcn_mfma_f32_16x16x32_f16(ah[kb], *(const half8*)(brow + kb * 32), c, 0, 0, 0);
        float bias = f32 ? ((const float*)b2raw)[ct * 16 + m] : b2f(b2raw[ct * 16 + m]);
        #pragma unroll
        for (int r = 0; r < 4; ++r) {
            float v = c[r] + bias;
            size_t o = (size_t)(node0 + quad * 4 + r) * 128 + ct * 16 + m;
            if (f32) ((float*)outraw)[o] = v;
            else     outraw[o] = f2b(v);
        }
    }
}

// ================= host =================
extern "C" void kernel_launch(void* const* d_in, const int* in_sizes, int n_in,
                              void* d_out, int out_size, void* d_ws, size_t ws_size,
                              hipStream_t stream) {
    const uint16_t* x    = (const uint16_t*)d_in[0];
    const int*      eidx = (const int*)     d_in[1];
    const uint16_t* ew   = (const uint16_t*)d_in[2];
    const uint16_t* w1   = (const uint16_t*)d_in[3];
    const uint16_t* b1   = (const uint16_t*)d_in[4];
    const uint16_t* w2   = (const uint16_t*)d_in[5];
    const uint16_t* b2   = (const uint16_t*)d_in[6];
    const uint16_t* eps  = (const uint16_t*)d_in[7];
    uint16_t*       out  = (uint16_t*)d_out;
    int* ws = (int*)d_ws;

    // ONE 0xFF memset covers: counters (-1), overflow counter (-1), overflow
    // pairs (garbage, bounded by novf), and buckets (NaN pad entries).
    hipMemsetAsync((char*)d_ws + (size_t)CNT_OFF * 4, 0xFF,
                   (size_t)(BKT_OFF + (size_t)NN * CAP - CNT_OFF) * 4, stream);
    prep_fill_kernel<<<FILL_BLKS + PX_BLKS + PW_BLKS, 256, 0, stream>>>(
        x, eidx, ew, w1, w2, ws);
    gmlp_kernel<<<NN / 16, 256, 0, stream>>>(x, eidx, b1, b2, eps, ws, out);
}